// Round 1
// baseline (722.421 us; speedup 1.0000x reference)
//
#include <hip/hip_runtime.h>

#define IMG_H 2048
#define IMG_W 2048
#define HALF 10                     // max_coc // 2
#define TILE_H 64
#define TILE_W 16
#define LDS_H (TILE_H + 2*HALF)     // 84
#define LDS_W (TILE_W + 2*HALF)     // 36
#define NSTAGE (LDS_H * LDS_W)      // 3024

// Gather form of the spatially-variant defocus scatter.
// out[q] = sum_{o in [-10,10]^2} img[q+o] * w_{k(q+o)}(o)
//   blur source (k>1):  w = exp(-d2 * 18/k^2) * 36/(2*pi*k^2), gated by max(|oy|,|ox|) <= k>>1
//   identity source (k<=1): weight 1 at o==0 only (epilogue; hk=0 masks it in main loop)
__global__ __launch_bounds__(256)
void defocus_gather_kernel(const float* __restrict__ img,
                           const int* __restrict__ ks,
                           float* __restrict__ out)
{
    __shared__ float4 tile[NSTAGE];

    const int tid = threadIdx.x;
    const int bx0 = blockIdx.x * TILE_W;
    const int by0 = blockIdx.y * TILE_H;

    // ---- stage halo tile: rgb + kernel-size bits packed into float4 ----
    for (int idx = tid; idx < NSTAGE; idx += 256) {
        int r = idx / LDS_W;
        int c = idx - r * LDS_W;
        int gy = by0 - HALF + r;
        int gx = bx0 - HALF + c;
        float4 v = make_float4(0.0f, 0.0f, 0.0f, __int_as_float(0));
        if (gy >= 0 && gy < IMG_H && gx >= 0 && gx < IMG_W) {
            int p = gy * IMG_W + gx;
            v.x = img[p * 3 + 0];
            v.y = img[p * 3 + 1];
            v.z = img[p * 3 + 2];
            v.w = __int_as_float(ks[p]);
        }
        tile[idx] = v;
    }
    __syncthreads();

    // 4x1 register blocking: thread (ty,tx) computes output rows by0+4*ty+i, col bx0+tx
    const int ty = tid >> 4;     // 0..15
    const int tx = tid & 15;     // 0..15

    float ar[4] = {0.f, 0.f, 0.f, 0.f};
    float ag[4] = {0.f, 0.f, 0.f, 0.f};
    float ab[4] = {0.f, 0.f, 0.f, 0.f};

    const float4* base = &tile[(ty * 4) * LDS_W + tx];

    for (int sy = 0; sy < TILE_H / TILE_W + 20; ++sy) { /* placeholder guard */ }

    for (int sy = 0; sy < 24; ++sy) {
        const int rowoff = sy * LDS_W;
        #pragma unroll 3
        for (int sx = 0; sx < 21; ++sx) {
            float4 f = base[rowoff + sx];
            int k  = __float_as_int(f.w);
            int hk = k >> 1;
            bool blur = (k > 1);
            float kk  = (float)(k * k);
            float rk2 = __builtin_amdgcn_rcpf(kk);      // 1/k^2 (inf for k=0; masked)
            float c1n = -25.968517f * rk2;              // -18*log2(e)/k^2
            float c2  =   5.7295780f * rk2;             // 36/(2*pi*k^2)

            const int ox  = sx - HALF;                  // wave-uniform
            const int ax  = ox < 0 ? -ox : ox;
            const int ox2 = ox * ox;
            #pragma unroll
            for (int i = 0; i < 4; ++i) {
                int oy = sy - HALF - i;                 // wave-uniform
                int ay = oy < 0 ? -oy : oy;
                int m  = ay > ax ? ay : ax;
                float d2 = (float)(oy * oy + ox2);
                float w = __builtin_amdgcn_exp2f(d2 * c1n) * c2;
                w = (blur && (m <= hk)) ? w : 0.0f;     // cndmask kills inf/NaN from k<=1
                ar[i] += f.x * w;
                ag[i] += f.y * w;
                ab[i] += f.z * w;
            }
        }
    }

    // ---- identity pass-through for k<=1 pixels ----
    #pragma unroll
    for (int i = 0; i < 4; ++i) {
        float4 f = tile[(ty * 4 + i + HALF) * LDS_W + (tx + HALF)];
        int k = __float_as_int(f.w);
        if (k <= 1) { ar[i] += f.x; ag[i] += f.y; ab[i] += f.z; }
    }

    // ---- store ----
    #pragma unroll
    for (int i = 0; i < 4; ++i) {
        int gy = by0 + ty * 4 + i;
        int gx = bx0 + tx;
        int p  = (gy * IMG_W + gx) * 3;
        out[p + 0] = ar[i];
        out[p + 1] = ag[i];
        out[p + 2] = ab[i];
    }
}

extern "C" void kernel_launch(void* const* d_in, const int* in_sizes, int n_in,
                              void* d_out, int out_size, void* d_ws, size_t ws_size,
                              hipStream_t stream) {
    const float* img = (const float*)d_in[0];
    const int*   ks  = (const int*)d_in[1];
    // d_in[2] = max_coc (scalar, always 21 per setup) — window radius hardcoded to 10.
    float* out = (float*)d_out;

    dim3 grid(IMG_W / TILE_W, IMG_H / TILE_H);   // 128 x 32
    dim3 block(256);
    defocus_gather_kernel<<<grid, block, 0, stream>>>(img, ks, out);
}

// Round 2
// 396.397 us; speedup vs baseline: 1.8225x; 1.8225x over previous
//
#include <hip/hip_runtime.h>
#include <hip/hip_fp16.h>

#define IMG_W 2048
#define IMG_H 2048
#define HALF  10          // max_coc // 2
#define TILE_H 32         // output rows per block
#define TILE_W 64         // output cols per block
#define LH (TILE_H + 2*HALF)   // 52 halo rows
#define LW (TILE_W + 2*HALF)   // 84 halo cols (multiple of 4 -> swizzle safe)
#define NSTG (LH * LW)         // 4368 staged pixels

// LUT geometry: lut[k][row][pos], f16.
//   row = (oy+10)+1, rows 0..22 (rows 0 and 22 are zero pads)
//   pos = (ox+10)+3, pos 3..23 valid, pos 0..2 / 24..27 zero pads
#define L_COLS 28
#define L_RSB  56              // row stride bytes (28 f16)
#define L_KSB  1292            // plane stride bytes = 323 dwords (odd -> k spreads banks)
#define L_U32  (22 * L_KSB / 4)  // 7106 uints

__device__ __forceinline__ float lo16(uint u) {
    return __half2float(__ushort_as_half((unsigned short)(u & 0xffffu)));
}
__device__ __forceinline__ float hi16(uint u) {
    return __half2float(__ushort_as_half((unsigned short)(u >> 16)));
}
__device__ __forceinline__ uint pack2(float a, float b) {
    return (uint)__half_as_ushort(__float2half(a)) |
           ((uint)__half_as_ushort(__float2half(b)) << 16);
}
// injective column swizzle: spreads 4-px-strided lane accesses over all 16 px slots
__device__ __forceinline__ int swz(int c) {
    return c ^ (((c >> 2) + (c >> 4)) & 3);
}

__global__ __launch_bounds__(256)
void defocus_lut_kernel(const float* __restrict__ img,
                        const int* __restrict__ ks,
                        float* __restrict__ out)
{
    __shared__ uint2 tile[NSTG];     // per px: {f16 r | f16 g, f16 b | f16 k}  8B
    __shared__ uint  lut[L_U32];     // f16 weight table, pair-packed along ox

    const int tid = threadIdx.x;
    const int X0 = blockIdx.x * TILE_W;
    const int Y0 = blockIdx.y * TILE_H;

    // ---- build weight LUT (gate + identity baked in, zero-padded borders) ----
    for (int i = tid; i < 22 * 23 * L_COLS; i += 256) {
        int k   = i / (23 * L_COLS);
        int rm  = i - k * 23 * L_COLS;
        int row = rm / L_COLS;
        int pos = rm - row * L_COLS;
        int oy = row - 1 - HALF;           // valid rows 1..21
        int ox = pos - 3 - HALF;           // valid pos 3..23
        float w = 0.0f;
        bool valid = (row >= 1) && (row <= 21) && (pos >= 3) && (pos <= 23);
        if (valid) {
            if (k <= 1) {
                w = (oy == 0 && ox == 0) ? 1.0f : 0.0f;
            } else {
                int hk = k >> 1;
                if (abs(oy) <= hk && abs(ox) <= hk) {
                    float kk = (float)(k * k);
                    float d2 = (float)(oy * oy + ox * ox);
                    w = expf(-d2 * 18.0f / kk) * 5.7295780f / kk;  // 36/(2*pi*k^2)
                }
            }
        }
        unsigned short hb = __half_as_ushort(__float2half(w));
        // 16-bit store into the uint-backed LDS array
        reinterpret_cast<unsigned short*>(lut)[(k * L_KSB + row * L_RSB) / 2 + pos] = hb;
    }

    // ---- stage halo tile as f16 {r,g,b,k}, column-swizzled ----
    for (int i = tid; i < NSTG; i += 256) {
        int r = i / LW;
        int c = i - r * LW;
        int gy = Y0 - HALF + r;
        int gx = X0 - HALF + c;
        float fr = 0.f, fg = 0.f, fb = 0.f, fk = 0.f;
        if (gy >= 0 && gy < IMG_H && gx >= 0 && gx < IMG_W) {
            int p = gy * IMG_W + gx;
            fr = img[p * 3 + 0];
            fg = img[p * 3 + 1];
            fb = img[p * 3 + 2];
            fk = (float)ks[p];
        }
        tile[r * LW + swz(c)] = make_uint2(pack2(fr, fg), pack2(fb, fk));
    }
    __syncthreads();

    // ---- main gather: thread (ty,tx) owns output rows ty*2+{0,1}, cols tx*4+{0..3} ----
    const int tx = tid & 15;
    const int ty = tid >> 4;
    const int colbase = tx * 4;   // thread's first output col within tile
    const int rowbase = ty * 2;   // thread's first output row within tile

    float acc[2][4][3];
    #pragma unroll
    for (int r = 0; r < 2; ++r)
        #pragma unroll
        for (int m = 0; m < 4; ++m)
            acc[r][m][0] = acc[r][m][1] = acc[r][m][2] = 0.f;

    for (int a = 0; a < 22; ++a) {            // source rows: sy = yc-10+a
        const uint2* rowp = &tile[(rowbase + a) * LW];
        #pragma unroll
        for (int b = 0; b < 24; ++b) {        // source cols: sx = xc-10+b
            uint2 p = rowp[swz(colbase + b)];
            float pr = lo16(p.x), pg = hi16(p.x), pb = lo16(p.y);
            float kf = hi16(p.y);
            int kbyte = (int)(kf * (float)L_KSB);   // exact: k*1292

            #pragma unroll
            for (int r = 0; r < 2; ++r) {
                // LUT row for this (source row, output row r): arr row = a+1-r
                int rbyte = kbyte + (a + 1 - r) * L_RSB;
                // taps m=0..3 read pos = b+3-m  (w_m below)
                float w0, w1, w2, w3;
                if ((b & 1) == 0) {
                    // pos run [b, b+3], b even -> 2 aligned pair reads
                    uint q0 = lut[(rbyte + 2 * b) >> 2];        // pos b, b+1
                    uint q1 = lut[(rbyte + 2 * b + 4) >> 2];    // pos b+2, b+3
                    w3 = lo16(q0); w2 = hi16(q0); w1 = lo16(q1); w0 = hi16(q1);
                } else {
                    // b odd -> 3 aligned pair reads, static half-picks
                    uint q0 = lut[(rbyte + 2 * (b - 1)) >> 2];  // pos b-1, b
                    uint q1 = lut[(rbyte + 2 * (b + 1)) >> 2];  // pos b+1, b+2
                    uint q2 = lut[(rbyte + 2 * (b + 3)) >> 2];  // pos b+3, b+4
                    w3 = hi16(q0); w2 = lo16(q1); w1 = hi16(q1); w0 = lo16(q2);
                }
                acc[r][0][0] += pr * w0; acc[r][0][1] += pg * w0; acc[r][0][2] += pb * w0;
                acc[r][1][0] += pr * w1; acc[r][1][1] += pg * w1; acc[r][1][2] += pb * w1;
                acc[r][2][0] += pr * w2; acc[r][2][1] += pg * w2; acc[r][2][2] += pb * w2;
                acc[r][3][0] += pr * w3; acc[r][3][1] += pg * w3; acc[r][3][2] += pb * w3;
            }
        }
    }

    // ---- store ----
    #pragma unroll
    for (int r = 0; r < 2; ++r) {
        int gy = Y0 + rowbase + r;
        #pragma unroll
        for (int m = 0; m < 4; ++m) {
            int gx = X0 + colbase + m;
            int o = (gy * IMG_W + gx) * 3;
            out[o + 0] = acc[r][m][0];
            out[o + 1] = acc[r][m][1];
            out[o + 2] = acc[r][m][2];
        }
    }
}

extern "C" void kernel_launch(void* const* d_in, const int* in_sizes, int n_in,
                              void* d_out, int out_size, void* d_ws, size_t ws_size,
                              hipStream_t stream) {
    const float* img = (const float*)d_in[0];
    const int*   ks  = (const int*)d_in[1];
    float* out = (float*)d_out;

    dim3 grid(IMG_W / TILE_W, IMG_H / TILE_H);   // 32 x 64
    dim3 block(256);
    defocus_lut_kernel<<<grid, block, 0, stream>>>(img, ks, out);
}

// Round 3
// 278.496 us; speedup vs baseline: 2.5940x; 1.4233x over previous
//
#include <hip/hip_runtime.h>
#include <hip/hip_fp16.h>

#define IMG_W 2048
#define IMG_H 2048
#define HALF  10          // max_coc // 2
#define TILE_H 32         // output rows per block
#define TILE_W 64         // output cols per block
#define LH (TILE_H + 2*HALF)   // 52 halo rows
#define LW (TILE_W + 2*HALF)   // 84 halo cols
#define NSTG (LH * LW)         // 4368 staged pixels

// LUT geometry: lut[k][row][pos], f16.
//   row = (oy+10)+1, rows 0..22 (rows 0 and 22 zero pads)
//   pos = (ox+10)+3, pos 3..23 valid, 0..2 / 24..27 zero pads
#define L_COLS 28
#define L_RSB  56                // row stride bytes
#define L_KSB  1292              // plane stride bytes = 323 dwords (odd -> k spreads banks)
#define L_U32  (22 * L_KSB / 4)

__device__ __forceinline__ __half2 h2(uint u)  { union { uint a; __half2 b; } c; c.a = u; return c.b; }
__device__ __forceinline__ uint   pack2(float a, float b) {
    return (uint)__half_as_ushort(__float2half(a)) |
           ((uint)__half_as_ushort(__float2half(b)) << 16);
}
// injective column swizzle: spreads 4-px-strided lane accesses over all 16 px slots
__device__ __forceinline__ int swz(int c) {
    return c ^ (((c >> 2) + (c >> 4)) & 3);
}

__global__ __launch_bounds__(256)
void defocus_pk_kernel(const float* __restrict__ img,
                       const int* __restrict__ ks,
                       float* __restrict__ out)
{
    __shared__ uint2 tile[NSTG];   // per px: {f16 r | f16 g, f16 b | u16 koff=k*1292}
    __shared__ uint  lut[L_U32];   // f16 weights, pair-packed along pos

    const int tid = threadIdx.x;
    const int X0 = blockIdx.x * TILE_W;
    const int Y0 = blockIdx.y * TILE_H;

    // ---- build weight LUT (gate + identity baked in, zero borders) ----
    for (int i = tid; i < 22 * 23 * L_COLS; i += 256) {
        int k   = i / (23 * L_COLS);
        int rm  = i - k * 23 * L_COLS;
        int row = rm / L_COLS;
        int pos = rm - row * L_COLS;
        int oy = row - 1 - HALF;
        int ox = pos - 3 - HALF;
        float w = 0.0f;
        if (row >= 1 && row <= 21 && pos >= 3 && pos <= 23) {
            if (k <= 1) {
                w = (oy == 0 && ox == 0) ? 1.0f : 0.0f;
            } else {
                int hk = k >> 1;
                if (abs(oy) <= hk && abs(ox) <= hk) {
                    float kk = (float)(k * k);
                    float d2 = (float)(oy * oy + ox * ox);
                    w = expf(-d2 * 18.0f / kk) * 5.7295780f / kk;
                }
            }
        }
        reinterpret_cast<unsigned short*>(lut)[(k * L_KSB + row * L_RSB) / 2 + pos] =
            __half_as_ushort(__float2half(w));
    }

    // ---- stage halo tile: f16 rgb + raw u16 LUT plane byte-offset ----
    for (int i = tid; i < NSTG; i += 256) {
        int r = i / LW;
        int c = i - r * LW;
        int gy = Y0 - HALF + r;
        int gx = X0 - HALF + c;
        float fr = 0.f, fg = 0.f, fb = 0.f;
        uint koff = 0;
        if (gy >= 0 && gy < IMG_H && gx >= 0 && gx < IMG_W) {
            int p = gy * IMG_W + gx;
            fr = img[p * 3 + 0];
            fg = img[p * 3 + 1];
            fb = img[p * 3 + 2];
            koff = (uint)(ks[p] * L_KSB);
        }
        uint2 v;
        v.x = pack2(fr, fg);
        v.y = (pack2(fb, 0.f) & 0xffffu) | (koff << 16);
        tile[r * LW + swz(c)] = v;
    }
    __syncthreads();

    // ---- main gather: thread (ty,tx) owns rows rowbase+{0,1}, cols colbase+{0..3} ----
    const int tx = tid & 15;
    const int ty = tid >> 4;
    const int colbase = tx * 4;
    const int rowbase = ty * 2;

    // precomputed swizzled pixel byte offsets (static-indexed -> stays in VGPRs)
    int pxoff[24];
    #pragma unroll
    for (int b = 0; b < 24; ++b) pxoff[b] = swz(colbase + b) * 8;

    const __half2 hz = h2(0u);
    __half2 a32[2][3], a10[2][3];        // f16 pair accs: (col3,col2) and (col1,col0)
    float mc[2][4][3];                   // f32 masters [r][col][ch]
    #pragma unroll
    for (int r = 0; r < 2; ++r)
        #pragma unroll
        for (int c = 0; c < 3; ++c) {
            a32[r][c] = hz; a10[r][c] = hz;
            mc[r][0][c] = mc[r][1][c] = mc[r][2][c] = mc[r][3][c] = 0.f;
        }

    const char* lutB = (const char*)lut;

    for (int a = 0; a < 22; ++a) {
        const char* rowp = (const char*)&tile[(rowbase + a) * LW];
        const int rowoff1 = (a + 1) * L_RSB;   // LUT row for output row r=0
        const int rowoff0 = a * L_RSB;         // LUT row for output row r=1

        #pragma unroll
        for (int b = 0; b < 24; ++b) {
            uint2 p = *(const uint2*)(rowp + pxoff[b]);
            int koff = (int)(p.y >> 16);
            uint rr = __builtin_amdgcn_perm(p.x, p.x, 0x01000100);  // (r,r)
            uint gg = __builtin_amdgcn_perm(p.x, p.x, 0x03020302);  // (g,g)
            uint bb = __builtin_amdgcn_perm(p.y, p.y, 0x01000100);  // (b,b)
            const char* kb = lutB + koff;

            #pragma unroll
            for (int r = 0; r < 2; ++r) {
                const char* rb = kb + (r ? rowoff0 : rowoff1);
                uint w32, w10;   // weight pairs: (pos b,b+1)=(col3,col2), (pos b+2,b+3)=(col1,col0)
                if ((b & 1) == 0) {
                    w32 = *(const uint*)(rb + 2 * b);
                    w10 = *(const uint*)(rb + 2 * b + 4);
                } else {
                    uint q0 = *(const uint*)(rb + 2 * (b - 1));
                    uint q1 = *(const uint*)(rb + 2 * (b + 1));
                    uint q2 = *(const uint*)(rb + 2 * (b + 3));
                    w32 = __builtin_amdgcn_alignbit(q1, q0, 16);
                    w10 = __builtin_amdgcn_alignbit(q2, q1, 16);
                }
                a32[r][0] = __hfma2(h2(rr), h2(w32), a32[r][0]);
                a32[r][1] = __hfma2(h2(gg), h2(w32), a32[r][1]);
                a32[r][2] = __hfma2(h2(bb), h2(w32), a32[r][2]);
                a10[r][0] = __hfma2(h2(rr), h2(w10), a10[r][0]);
                a10[r][1] = __hfma2(h2(gg), h2(w10), a10[r][1]);
                a10[r][2] = __hfma2(h2(bb), h2(w10), a10[r][2]);
            }
        }

        // flush f16 partials (<=48 taps) into f32 masters every 2 source rows
        if (a & 1) {
            #pragma unroll
            for (int r = 0; r < 2; ++r)
                #pragma unroll
                for (int c = 0; c < 3; ++c) {
                    float2 f3 = __half22float2(a32[r][c]);
                    float2 f1 = __half22float2(a10[r][c]);
                    mc[r][3][c] += f3.x; mc[r][2][c] += f3.y;
                    mc[r][1][c] += f1.x; mc[r][0][c] += f1.y;
                    a32[r][c] = hz; a10[r][c] = hz;
                }
        }
    }

    // ---- store ----
    #pragma unroll
    for (int r = 0; r < 2; ++r) {
        int gy = Y0 + rowbase + r;
        #pragma unroll
        for (int m = 0; m < 4; ++m) {
            int gx = X0 + colbase + m;
            int o = (gy * IMG_W + gx) * 3;
            out[o + 0] = mc[r][m][0];
            out[o + 1] = mc[r][m][1];
            out[o + 2] = mc[r][m][2];
        }
    }
}

extern "C" void kernel_launch(void* const* d_in, const int* in_sizes, int n_in,
                              void* d_out, int out_size, void* d_ws, size_t ws_size,
                              hipStream_t stream) {
    const float* img = (const float*)d_in[0];
    const int*   ks  = (const int*)d_in[1];
    float* out = (float*)d_out;

    dim3 grid(IMG_W / TILE_W, IMG_H / TILE_H);   // 32 x 64
    dim3 block(256);
    defocus_pk_kernel<<<grid, block, 0, stream>>>(img, ks, out);
}

// Round 4
// 276.167 us; speedup vs baseline: 2.6159x; 1.0084x over previous
//
#include <hip/hip_runtime.h>
#include <hip/hip_fp16.h>

#define IMG_W 2048
#define IMG_H 2048
#define HALF  10          // max_coc // 2
#define TILE_H 32
#define TILE_W 64
#define LH (TILE_H + 2*HALF)   // 52
#define LW (TILE_W + 2*HALF)   // 84
#define NSTG (LH * LW)         // 4368

// Folded LUT: lut[k][row][pos], f16, row = |oy| in 0..11 (row 11 = zero pad),
// pos = ox+13, valid 3..23, zero pads 0..2 / 24..27.
#define L_RSB  56              // row stride bytes (28 f16)
#define L_KSB  676             // plane stride bytes = 169 dwords (odd -> k spreads banks)
#define LUT_BYTES (22 * L_KSB) // 14872 (8B aligned)
#define TILE_OFF  LUT_BYTES
#define SMEM_BYTES (TILE_OFF + NSTG * 8)   // 49816 -> 3 blocks/CU

__device__ __forceinline__ __half2 h2(uint u)  { union { uint a; __half2 b; } c; c.a = u; return c.b; }
__device__ __forceinline__ uint pack2(float a, float b) {
    return (uint)__half_as_ushort(__float2half(a)) |
           ((uint)__half_as_ushort(__float2half(b)) << 16);
}
// injective column swizzle: spreads 4-px-strided lane accesses over all 16 px slots
__device__ __forceinline__ int swz(int c) {
    return c ^ (((c >> 2) + (c >> 4)) & 3);
}

// One source row: r0 reads LUT row at +O0D dwords, r1 at +O1D dwords from baserow.
template<int O0D, int O1D>
__device__ __forceinline__ void gather_row(const char* smemc, int rowbase, int a, int baserow,
                                           const int* pxoff, __half2 a32[2][3], __half2 a10[2][3])
{
    const char* rowp = smemc + TILE_OFF + (rowbase + a) * (LW * 8);
    const int sbase = baserow * L_RSB;     // wave-uniform (SALU)

    #pragma unroll
    for (int b = 0; b < 24; ++b) {
        uint2 p = *(const uint2*)(rowp + pxoff[b]);
        uint rr = __builtin_amdgcn_perm(p.x, p.x, 0x01000100);  // (r,r)
        uint gg = __builtin_amdgcn_perm(p.x, p.x, 0x03020302);  // (g,g)
        uint bb = __builtin_amdgcn_perm(p.y, p.y, 0x01000100);  // (b,b)
        const uint* wp = (const uint*)(smemc + ((p.y >> 16) + sbase));  // plane+baserow

        #pragma unroll
        for (int r = 0; r < 2; ++r) {
            const int OD = r ? O1D : O0D;
            uint w32, w10;   // (pos b,b+1)=(col3,col2), (pos b+2,b+3)=(col1,col0)
            if ((b & 1) == 0) {
                w32 = wp[OD + (b >> 1)];
                w10 = wp[OD + (b >> 1) + 1];
            } else {
                uint q0 = wp[OD + (b >> 1)];        // pos b-1,b
                uint q1 = wp[OD + (b >> 1) + 1];    // pos b+1,b+2
                uint q2 = wp[OD + (b >> 1) + 2];    // pos b+3,b+4
                w32 = __builtin_amdgcn_alignbit(q1, q0, 16);
                w10 = __builtin_amdgcn_alignbit(q2, q1, 16);
            }
            a32[r][0] = __hfma2(h2(rr), h2(w32), a32[r][0]);
            a32[r][1] = __hfma2(h2(gg), h2(w32), a32[r][1]);
            a32[r][2] = __hfma2(h2(bb), h2(w32), a32[r][2]);
            a10[r][0] = __hfma2(h2(rr), h2(w10), a10[r][0]);
            a10[r][1] = __hfma2(h2(gg), h2(w10), a10[r][1]);
            a10[r][2] = __hfma2(h2(bb), h2(w10), a10[r][2]);
        }
    }
}

__global__ __launch_bounds__(256)
void defocus_fold_kernel(const float* __restrict__ img,
                         const int* __restrict__ ks,
                         float* __restrict__ out)
{
    __shared__ __align__(16) char smem[SMEM_BYTES];

    const int tid = threadIdx.x;
    const int X0 = blockIdx.x * TILE_W;
    const int Y0 = blockIdx.y * TILE_H;

    // ---- build folded weight LUT ----
    for (int i = tid; i < 22 * 12 * 28; i += 256) {
        int k   = i / (12 * 28);
        int rm  = i - k * 12 * 28;
        int row = rm / 28;                 // |oy|
        int pos = rm - row * 28;
        int ox  = pos - 13;
        float w = 0.0f;
        if (row <= 10 && pos >= 3 && pos <= 23) {
            if (k <= 1) {
                w = (row == 0 && ox == 0) ? 1.0f : 0.0f;
            } else {
                int hk = k >> 1;
                if (row <= hk && abs(ox) <= hk) {
                    float kk = (float)(k * k);
                    float d2 = (float)(row * row + ox * ox);
                    w = expf(-d2 * 18.0f / kk) * 5.7295780f / kk;
                }
            }
        }
        *(unsigned short*)(smem + k * L_KSB + row * L_RSB + pos * 2) =
            __half_as_ushort(__float2half(w));
    }

    // ---- stage halo tile: f16 rgb + u16 plane byte-offset (k*676) ----
    for (int i = tid; i < NSTG; i += 256) {
        int r = i / LW;
        int c = i - r * LW;
        int gy = Y0 - HALF + r;
        int gx = X0 - HALF + c;
        float fr = 0.f, fg = 0.f, fb = 0.f;
        uint koff = 0;
        if (gy >= 0 && gy < IMG_H && gx >= 0 && gx < IMG_W) {
            int p = gy * IMG_W + gx;
            fr = img[p * 3 + 0];
            fg = img[p * 3 + 1];
            fb = img[p * 3 + 2];
            koff = (uint)(ks[p] * L_KSB);
        }
        uint2 v;
        v.x = pack2(fr, fg);
        v.y = (pack2(fb, 0.f) & 0xffffu) | (koff << 16);
        *(uint2*)(smem + TILE_OFF + (r * LW + swz(c)) * 8) = v;
    }
    __syncthreads();

    const int tx = tid & 15;
    const int ty = tid >> 4;
    const int colbase = tx * 4;
    const int rowbase = ty * 2;

    int pxoff[24];
    #pragma unroll
    for (int b = 0; b < 24; ++b) pxoff[b] = swz(colbase + b) * 8;

    const __half2 hz = h2(0u);
    __half2 a32[2][3], a10[2][3];
    float mc[2][4][3];
    #pragma unroll
    for (int r = 0; r < 2; ++r)
        #pragma unroll
        for (int c = 0; c < 3; ++c) {
            a32[r][c] = hz; a10[r][c] = hz;
            mc[r][0][c] = mc[r][1][c] = mc[r][2][c] = mc[r][3][c] = 0.f;
        }

#define FLUSH()                                                        \
    { _Pragma("unroll")                                                \
      for (int r = 0; r < 2; ++r) {                                    \
          _Pragma("unroll")                                            \
          for (int c = 0; c < 3; ++c) {                                \
              float2 f3 = __half22float2(a32[r][c]);                   \
              float2 f1 = __half22float2(a10[r][c]);                   \
              mc[r][3][c] += f3.x; mc[r][2][c] += f3.y;                \
              mc[r][1][c] += f1.x; mc[r][0][c] += f1.y;                \
              a32[r][c] = hz; a10[r][c] = hz;                          \
          }                                                            \
      } }

    // half A: a=0..10, baserow=10-a, r0 at +0, r1 at +14 dwords
    #pragma unroll 1
    for (int a = 0; a < 10; a += 2) {
        gather_row<0, 14>(smem, rowbase, a,     10 - a,     pxoff, a32, a10);
        gather_row<0, 14>(smem, rowbase, a + 1, 10 - a - 1, pxoff, a32, a10);
        FLUSH();
    }
    gather_row<0, 14>(smem, rowbase, 10, 0, pxoff, a32, a10);
    // half B: a=11..21, baserow=a-11, r1 at +0, r0 at +14 dwords
    gather_row<14, 0>(smem, rowbase, 11, 0, pxoff, a32, a10);
    FLUSH();
    #pragma unroll 1
    for (int a = 12; a < 22; a += 2) {
        gather_row<14, 0>(smem, rowbase, a,     a - 11,     pxoff, a32, a10);
        gather_row<14, 0>(smem, rowbase, a + 1, a + 1 - 11, pxoff, a32, a10);
        FLUSH();
    }

    // ---- store ----
    #pragma unroll
    for (int r = 0; r < 2; ++r) {
        int gy = Y0 + rowbase + r;
        #pragma unroll
        for (int m = 0; m < 4; ++m) {
            int gx = X0 + colbase + m;
            int o = (gy * IMG_W + gx) * 3;
            out[o + 0] = mc[r][m][0];
            out[o + 1] = mc[r][m][1];
            out[o + 2] = mc[r][m][2];
        }
    }
}

extern "C" void kernel_launch(void* const* d_in, const int* in_sizes, int n_in,
                              void* d_out, int out_size, void* d_ws, size_t ws_size,
                              hipStream_t stream) {
    const float* img = (const float*)d_in[0];
    const int*   ks  = (const int*)d_in[1];
    float* out = (float*)d_out;

    dim3 grid(IMG_W / TILE_W, IMG_H / TILE_H);   // 32 x 64
    dim3 block(256);
    defocus_fold_kernel<<<grid, block, 0, stream>>>(img, ks, out);
}

// Round 5
// 270.395 us; speedup vs baseline: 2.6717x; 1.0213x over previous
//
#include <hip/hip_runtime.h>
#include <hip/hip_fp16.h>

#define IMG_W 2048
#define IMG_H 2048
#define HALF  10          // max_coc // 2
#define TILE_H 32
#define TILE_W 64
#define LH (TILE_H + 2*HALF)   // 52
#define LW (TILE_W + 2*HALF)   // 84
#define NSTG (LH * LW)         // 4368

// Folded LUT (f16): lut[k][row][pos], row = |oy| in 0..11 (row 11 zero),
// pos = ox+13, valid 3..23, zero pads 0..2 / 24..27.  Dword-granular:
#define L_RSD 14               // row stride dwords (28 f16)
#define L_KSD 169              // plane stride dwords (odd -> per-lane-k bank spread)
#define L_NDW (22 * L_KSD)     // 3718 dwords = 14872 B

__device__ __forceinline__ __half2 h2(uint u)  { union { uint a; __half2 b; } c; c.a = u; return c.b; }
__device__ __forceinline__ uint pack2(float a, float b) {
    return (uint)__half_as_ushort(__float2half(a)) |
           ((uint)__half_as_ushort(__float2half(b)) << 16);
}
// injective column swizzle: spreads 4-px-strided lane accesses over all 16 px slots
__device__ __forceinline__ int swz(int c) {
    return c ^ (((c >> 2) + (c >> 4)) & 3);
}

__global__ __launch_bounds__(256)
void defocus_typed_kernel(const float* __restrict__ img,
                          const int* __restrict__ ks,
                          float* __restrict__ out)
{
    __shared__ uint  lut[L_NDW];    // 14872 B
    __shared__ uint2 tile[NSTG];    // 34944 B   (total 49816 B)

    const int tid = threadIdx.x;
    const int X0 = blockIdx.x * TILE_W;
    const int Y0 = blockIdx.y * TILE_H;

    // ---- build folded weight LUT (cold; casts ok here) ----
    for (int i = tid; i < 22 * 12 * 28; i += 256) {
        int k   = i / (12 * 28);
        int rm  = i - k * (12 * 28);
        int row = rm / 28;                 // |oy|
        int pos = rm - row * 28;
        int ox  = pos - 13;
        float w = 0.0f;
        if (row <= 10 && pos >= 3 && pos <= 23) {
            if (k <= 1) {
                w = (row == 0 && ox == 0) ? 1.0f : 0.0f;
            } else {
                int hk = k >> 1;
                if (row <= hk && abs(ox) <= hk) {
                    float kk = (float)(k * k);
                    float d2 = (float)(row * row + ox * ox);
                    w = expf(-d2 * 18.0f / kk) * 5.7295780f / kk;
                }
            }
        }
        reinterpret_cast<unsigned short*>(lut)[k * (2 * L_KSD) + row * 28 + pos] =
            __half_as_ushort(__float2half(w));
    }

    // ---- stage halo tile: {f16 r|g , f16 b | u16 koffd=k*169} ----
    for (int i = tid; i < NSTG; i += 256) {
        int r = i / LW;
        int c = i - r * LW;
        int gy = Y0 - HALF + r;
        int gx = X0 - HALF + c;
        float fr = 0.f, fg = 0.f, fb = 0.f;
        uint koffd = 0;
        if (gy >= 0 && gy < IMG_H && gx >= 0 && gx < IMG_W) {
            int p = gy * IMG_W + gx;
            fr = img[p * 3 + 0];
            fg = img[p * 3 + 1];
            fb = img[p * 3 + 2];
            koffd = (uint)(ks[p] * L_KSD);
        }
        uint2 v;
        v.x = pack2(fr, fg);
        v.y = (pack2(fb, 0.f) & 0xffffu) | (koffd << 16);
        tile[r * LW + swz(c)] = v;
    }
    __syncthreads();

    const int tx = tid & 15;
    const int ty = tid >> 4;
    const int colbase = tx * 4;
    const int rowbase = ty * 2;

    int pxidx[24];
    #pragma unroll
    for (int b = 0; b < 24; ++b) pxidx[b] = swz(colbase + b);

    const __half2 hz = h2(0u);
    __half2 a32[2][3], a10[2][3];   // f16 pair accs: (col3,col2), (col1,col0)
    float mc[2][4][3];              // f32 masters [r][col][ch]
    #pragma unroll
    for (int r = 0; r < 2; ++r)
        #pragma unroll
        for (int c = 0; c < 3; ++c) {
            a32[r][c] = hz; a10[r][c] = hz;
            mc[r][0][c] = mc[r][1][c] = mc[r][2][c] = mc[r][3][c] = 0.f;
        }

    // One source row aa: r0 reads LUT row BR+ (OD0/14), r1 row at OD1.
#define GROW(aa, OD0, OD1, BR)                                                     \
    { const int rowoff = (rowbase + (aa)) * LW;                                    \
      const uint wrow = (uint)((BR) * L_RSD);                                      \
      _Pragma("unroll")                                                            \
      for (int b = 0; b < 24; ++b) {                                               \
          uint2 p = tile[rowoff + pxidx[b]];                                       \
          __half2 hx = h2(p.x), hy = h2(p.y);                                      \
          __half2 rr = __low2half2(hx), gg = __high2half2(hx), bb = __low2half2(hy); \
          uint wbase = (p.y >> 16) + wrow;                                         \
          const int h = b >> 1;                                                    \
          uint w32a, w10a, w32b, w10b;                                             \
          if ((b & 1) == 0) {                                                      \
              w32a = lut[wbase + (OD0) + h]; w10a = lut[wbase + (OD0) + h + 1];    \
              w32b = lut[wbase + (OD1) + h]; w10b = lut[wbase + (OD1) + h + 1];    \
          } else {                                                                 \
              uint qa0 = lut[wbase + (OD0) + h];                                   \
              uint qa1 = lut[wbase + (OD0) + h + 1];                               \
              uint qa2 = lut[wbase + (OD0) + h + 2];                               \
              uint qb0 = lut[wbase + (OD1) + h];                                   \
              uint qb1 = lut[wbase + (OD1) + h + 1];                               \
              uint qb2 = lut[wbase + (OD1) + h + 2];                               \
              w32a = __builtin_amdgcn_alignbit(qa1, qa0, 16);                      \
              w10a = __builtin_amdgcn_alignbit(qa2, qa1, 16);                      \
              w32b = __builtin_amdgcn_alignbit(qb1, qb0, 16);                      \
              w10b = __builtin_amdgcn_alignbit(qb2, qb1, 16);                      \
          }                                                                        \
          a32[0][0] = __hfma2(rr, h2(w32a), a32[0][0]);                            \
          a32[0][1] = __hfma2(gg, h2(w32a), a32[0][1]);                            \
          a32[0][2] = __hfma2(bb, h2(w32a), a32[0][2]);                            \
          a10[0][0] = __hfma2(rr, h2(w10a), a10[0][0]);                            \
          a10[0][1] = __hfma2(gg, h2(w10a), a10[0][1]);                            \
          a10[0][2] = __hfma2(bb, h2(w10a), a10[0][2]);                            \
          a32[1][0] = __hfma2(rr, h2(w32b), a32[1][0]);                            \
          a32[1][1] = __hfma2(gg, h2(w32b), a32[1][1]);                            \
          a32[1][2] = __hfma2(bb, h2(w32b), a32[1][2]);                            \
          a10[1][0] = __hfma2(rr, h2(w10b), a10[1][0]);                            \
          a10[1][1] = __hfma2(gg, h2(w10b), a10[1][1]);                            \
          a10[1][2] = __hfma2(bb, h2(w10b), a10[1][2]);                            \
      } }

#define FLUSH()                                                        \
    { _Pragma("unroll")                                                \
      for (int r = 0; r < 2; ++r) {                                    \
          _Pragma("unroll")                                            \
          for (int c = 0; c < 3; ++c) {                                \
              float2 f3 = __half22float2(a32[r][c]);                   \
              float2 f1 = __half22float2(a10[r][c]);                   \
              mc[r][3][c] += f3.x; mc[r][2][c] += f3.y;                \
              mc[r][1][c] += f1.x; mc[r][0][c] += f1.y;                \
              a32[r][c] = hz; a10[r][c] = hz;                          \
          }                                                            \
      } }

    // half A: a=0..10, r0 row = 10-a (BR), r1 row = BR+1 (OD 14)
    #pragma unroll 1
    for (int a = 0; a < 10; a += 2) {
        GROW(a,     0, 14, 10 - a);
        GROW(a + 1, 0, 14, 9 - a);
        FLUSH();
    }
    GROW(10, 0, 14, 0);
    // half B: a=11..21, r1 row = a-11 (BR), r0 row = BR+1 (OD 14)
    GROW(11, 14, 0, 0);
    FLUSH();
    #pragma unroll 1
    for (int a = 12; a < 22; a += 2) {
        GROW(a,     14, 0, a - 11);
        GROW(a + 1, 14, 0, a - 10);
        FLUSH();
    }

    // ---- store ----
    #pragma unroll
    for (int r = 0; r < 2; ++r) {
        int gy = Y0 + rowbase + r;
        #pragma unroll
        for (int m = 0; m < 4; ++m) {
            int gx = X0 + colbase + m;
            int o = (gy * IMG_W + gx) * 3;
            out[o + 0] = mc[r][m][0];
            out[o + 1] = mc[r][m][1];
            out[o + 2] = mc[r][m][2];
        }
    }
#undef GROW
#undef FLUSH
}

extern "C" void kernel_launch(void* const* d_in, const int* in_sizes, int n_in,
                              void* d_out, int out_size, void* d_ws, size_t ws_size,
                              hipStream_t stream) {
    const float* img = (const float*)d_in[0];
    const int*   ks  = (const int*)d_in[1];
    float* out = (float*)d_out;

    dim3 grid(IMG_W / TILE_W, IMG_H / TILE_H);   // 32 x 64
    dim3 block(256);
    defocus_typed_kernel<<<grid, block, 0, stream>>>(img, ks, out);
}

// Round 6
// 200.602 us; speedup vs baseline: 3.6013x; 1.3479x over previous
//
#include <hip/hip_runtime.h>
#include <hip/hip_fp16.h>

#define IMG_W 2048
#define IMG_H 2048
#define HALF  10          // max_coc // 2
#define TILE_H 32
#define TILE_W 64
#define LH (TILE_H + 2*HALF)   // 52
#define LW (TILE_W + 2*HALF)   // 84
#define NSTG (LH * LW)         // 4368

// Separable LUT, one 37-dword plane per k (stride odd -> per-lane-k bank-spread):
//   dwords 0..21 : wy pairs; entry a = pack2(wy(k, a-10), wy(k, a-11))
//                  (lo feeds output row r0, hi feeds r1, at source row a)
//   dwords 22..35: wx pairs; dword 22+h = pack2(wx(k, 2h-13), wx(k, 2h-12))
//                  (pos = ox+13; valid pos 3..23, rest zero)
//   dword 36     : pad
#define L_KSD 37
#define L_NDW (22 * L_KSD)     // 814 dwords = 3256 B

__device__ __forceinline__ __half2 h2(uint u)  { union { uint a; __half2 b; } c; c.a = u; return c.b; }
__device__ __forceinline__ uint pack2(float a, float b) {
    return (uint)__half_as_ushort(__float2half(a)) |
           ((uint)__half_as_ushort(__float2half(b)) << 16);
}
// injective column swizzle: spreads 4-px-strided lane accesses over all 16 px slots
__device__ __forceinline__ int swz(int c) {
    return c ^ (((c >> 2) + (c >> 4)) & 3);
}

// weight factors: w(k,oy,ox) = wyv(k,oy) * wxv(k,ox); c2 folded into wy
__device__ __forceinline__ float wyv(int k, int oy) {
    int a = abs(oy), hk = k >> 1;
    if (a > hk) return 0.f;
    if (k <= 1) return 1.f;
    float kk = (float)(k * k);
    return expf(-(float)(oy * oy) * 18.f / kk) * 5.7295780f / kk;
}
__device__ __forceinline__ float wxv(int k, int ox) {
    int a = abs(ox), hk = k >> 1;
    if (a > hk) return 0.f;
    if (k <= 1) return 1.f;
    float kk = (float)(k * k);
    return expf(-(float)(ox * ox) * 18.f / kk);
}

__global__ __launch_bounds__(256)
void defocus_sep_kernel(const float* __restrict__ img,
                        const int* __restrict__ ks,
                        float* __restrict__ out)
{
    __shared__ uint  lutw[L_NDW];   // 3256 B
    __shared__ uint2 tile[NSTG];    // 34944 B   (total ~38.2 KB -> 4 blocks/CU)

    const int tid = threadIdx.x;
    const int X0 = blockIdx.x * TILE_W;
    const int Y0 = blockIdx.y * TILE_H;

    // ---- build separable LUT (dword-granular, no u16 races) ----
    for (int i = tid; i < L_NDW; i += 256) {
        int k = i / L_KSD;
        int d = i - k * L_KSD;
        float lo, hi;
        if (d < 22) {           // wy pair for source row a=d
            lo = wyv(k, d - 10);
            hi = wyv(k, d - 11);
        } else {                // wx pair, pos = 2(d-22), ox = pos-13
            int pos = (d - 22) * 2;
            lo = wxv(k, pos - 13);
            hi = wxv(k, pos - 12);
        }
        lutw[i] = pack2(lo, hi);
    }

    // ---- stage halo tile: {f16 r|g , f16 b | u16 kplane=k*37} ----
    for (int i = tid; i < NSTG; i += 256) {
        int r = i / LW;
        int c = i - r * LW;
        int gy = Y0 - HALF + r;
        int gx = X0 - HALF + c;
        float fr = 0.f, fg = 0.f, fb = 0.f;
        uint kp = 0;
        if (gy >= 0 && gy < IMG_H && gx >= 0 && gx < IMG_W) {
            int p = gy * IMG_W + gx;
            fr = img[p * 3 + 0];
            fg = img[p * 3 + 1];
            fb = img[p * 3 + 2];
            kp = (uint)(ks[p] * L_KSD);
        }
        uint2 v;
        v.x = pack2(fr, fg);
        v.y = (pack2(fb, 0.f) & 0xffffu) | (kp << 16);
        tile[r * LW + swz(c)] = v;
    }
    __syncthreads();

    const int tx = tid & 15;
    const int ty = tid >> 4;
    const int colbase = tx * 4;
    const int rowbase = ty * 2;

    int pxidx[24];
    #pragma unroll
    for (int b = 0; b < 24; ++b) pxidx[b] = swz(colbase + b);

    const __half2 hz = h2(0u);
    __half2 a32[2][3], a10[2][3];   // f16 pair accs: (col3,col2), (col1,col0)
    float mc[2][4][3];              // f32 masters [r][col][ch]
    #pragma unroll
    for (int r = 0; r < 2; ++r)
        #pragma unroll
        for (int c = 0; c < 3; ++c) {
            a32[r][c] = hz; a10[r][c] = hz;
            mc[r][0][c] = mc[r][1][c] = mc[r][2][c] = mc[r][3][c] = 0.f;
        }

#define ROW(aa)                                                                    \
    { const int rowoff = (rowbase + (aa)) * LW;                                    \
      _Pragma("unroll")                                                            \
      for (int b = 0; b < 24; ++b) {                                               \
          uint2 p = tile[rowoff + pxidx[b]];                                       \
          __half2 hx = h2(p.x), hy = h2(p.y);                                      \
          __half2 rr = __low2half2(hx), gg = __high2half2(hx), bb = __low2half2(hy); \
          const int wb = (int)(p.y >> 16);                                         \
          __half2 wy2 = h2(lutw[wb + (aa)]);                                       \
          __half2 wy0 = __low2half2(wy2), wy1 = __high2half2(wy2);                 \
          const int h = b >> 1;                                                    \
          uint w32, w10;   /* wx pairs: (pos b,b+1)=(col3,col2), (pos b+2,b+3)=(col1,col0) */ \
          if ((b & 1) == 0) {                                                      \
              w32 = lutw[wb + 22 + h];                                             \
              w10 = lutw[wb + 23 + h];                                             \
          } else {                                                                 \
              uint q0 = lutw[wb + 22 + h];                                         \
              uint q1 = lutw[wb + 23 + h];                                         \
              uint q2 = lutw[wb + 24 + h];                                         \
              w32 = __builtin_amdgcn_alignbit(q1, q0, 16);                         \
              w10 = __builtin_amdgcn_alignbit(q2, q1, 16);                         \
          }                                                                        \
          __half2 W320 = __hmul2(h2(w32), wy0), W100 = __hmul2(h2(w10), wy0);      \
          __half2 W321 = __hmul2(h2(w32), wy1), W101 = __hmul2(h2(w10), wy1);      \
          a32[0][0] = __hfma2(rr, W320, a32[0][0]);                                \
          a32[0][1] = __hfma2(gg, W320, a32[0][1]);                                \
          a32[0][2] = __hfma2(bb, W320, a32[0][2]);                                \
          a10[0][0] = __hfma2(rr, W100, a10[0][0]);                                \
          a10[0][1] = __hfma2(gg, W100, a10[0][1]);                                \
          a10[0][2] = __hfma2(bb, W100, a10[0][2]);                                \
          a32[1][0] = __hfma2(rr, W321, a32[1][0]);                                \
          a32[1][1] = __hfma2(gg, W321, a32[1][1]);                                \
          a32[1][2] = __hfma2(bb, W321, a32[1][2]);                                \
          a10[1][0] = __hfma2(rr, W101, a10[1][0]);                                \
          a10[1][1] = __hfma2(gg, W101, a10[1][1]);                                \
          a10[1][2] = __hfma2(bb, W101, a10[1][2]);                                \
      } }

#define FLUSH()                                                        \
    { _Pragma("unroll")                                                \
      for (int r = 0; r < 2; ++r) {                                    \
          _Pragma("unroll")                                            \
          for (int c = 0; c < 3; ++c) {                                \
              float2 f3 = __half22float2(a32[r][c]);                   \
              float2 f1 = __half22float2(a10[r][c]);                   \
              mc[r][3][c] += f3.x; mc[r][2][c] += f3.y;                \
              mc[r][1][c] += f1.x; mc[r][0][c] += f1.y;                \
              a32[r][c] = hz; a10[r][c] = hz;                          \
          }                                                            \
      } }

    // 22 source rows, flush f16 partials (<=48 taps) every 2 rows
    #pragma unroll 1
    for (int ap = 0; ap < 11; ++ap) {
        ROW(2 * ap);
        ROW(2 * ap + 1);
        FLUSH();
    }

    // ---- store ----
    #pragma unroll
    for (int r = 0; r < 2; ++r) {
        int gy = Y0 + rowbase + r;
        #pragma unroll
        for (int m = 0; m < 4; ++m) {
            int gx = X0 + colbase + m;
            int o = (gy * IMG_W + gx) * 3;
            out[o + 0] = mc[r][m][0];
            out[o + 1] = mc[r][m][1];
            out[o + 2] = mc[r][m][2];
        }
    }
#undef ROW
#undef FLUSH
}

extern "C" void kernel_launch(void* const* d_in, const int* in_sizes, int n_in,
                              void* d_out, int out_size, void* d_ws, size_t ws_size,
                              hipStream_t stream) {
    const float* img = (const float*)d_in[0];
    const int*   ks  = (const int*)d_in[1];
    float* out = (float*)d_out;

    dim3 grid(IMG_W / TILE_W, IMG_H / TILE_H);   // 32 x 64
    dim3 block(256);
    defocus_sep_kernel<<<grid, block, 0, stream>>>(img, ks, out);
}

// Round 7
// 194.116 us; speedup vs baseline: 3.7216x; 1.0334x over previous
//
#include <hip/hip_runtime.h>
#include <hip/hip_fp16.h>

#define IMG_W 2048
#define IMG_H 2048
#define HALF  10          // max_coc // 2
#define TILE_H 32
#define TILE_W 64
#define LH (TILE_H + 2*HALF)   // 52
#define LW (TILE_W + 2*HALF)   // 84
#define NSTG (LH * LW)         // 4368

// Separable LUT, one 51-dword plane per k (odd stride -> per-lane-k bank-spread):
//   dwords  0..21 : wy pairs; entry a = pack2(wy(a-10), wy(a-11))  (lo->r0, hi->r1)
//   dwords 22..35 : wx pairs;  22+h = pack2(wx(2h-13), wx(2h-12))   (pos 2h,2h+1)
//   dwords 36..49 : wx shifted; 36+j = pack2(wx(2j-12), wx(2j-11))  (pos 2j+1,2j+2)
//   dword  50     : pad
#define L_KSD 51
#define L_KSB 204              // byte plane stride (k*204 fits u16, dword-aligned)
#define L_NDW (22 * L_KSD)     // 1122 dwords = 4488 B

__device__ __forceinline__ __half2 h2(uint u)  { union { uint a; __half2 b; } c; c.a = u; return c.b; }
__device__ __forceinline__ uint pack2(float a, float b) {
    return (uint)__half_as_ushort(__float2half(a)) |
           ((uint)__half_as_ushort(__float2half(b)) << 16);
}
// weight factors: w(k,oy,ox) = wyv(k,oy) * wxv(k,ox); norm folded into wy
__device__ __forceinline__ float wyv(int k, int oy) {
    int a = abs(oy), hk = k >> 1;
    if (a > hk) return 0.f;
    if (k <= 1) return 1.f;
    float kk = (float)(k * k);
    return expf(-(float)(oy * oy) * 18.f / kk) * 5.7295780f / kk;
}
__device__ __forceinline__ float wxv(int k, int ox) {
    int a = abs(ox), hk = k >> 1;
    if (a > hk) return 0.f;
    if (k <= 1) return 1.f;
    float kk = (float)(k * k);
    return expf(-(float)(ox * ox) * 18.f / kk);
}

__global__ __launch_bounds__(256)
void defocus_imm_kernel(const float* __restrict__ img,
                        const int* __restrict__ ks,
                        float* __restrict__ out)
{
    __shared__ uint  lutw[L_NDW + 2];   // 4496 B (padded, keeps tile 16B-aligned)
    __shared__ uint2 tile[NSTG];        // 34944 B; [row][(c&3)*21 + (c>>2)]

    const int tid = threadIdx.x;
    const int X0 = blockIdx.x * TILE_W;
    const int Y0 = blockIdx.y * TILE_H;

    // ---- build separable LUT ----
    for (int i = tid; i < L_NDW; i += 256) {
        int k = i / L_KSD;
        int d = i - k * L_KSD;
        float lo = 0.f, hi = 0.f;
        if (d < 22) {                       // wy pair for source row a=d
            lo = wyv(k, d - 10);
            hi = wyv(k, d - 11);
        } else if (d < 36) {                // wx pair, pos (2h, 2h+1)
            int j = d - 22;
            lo = wxv(k, 2 * j - 13);
            hi = wxv(k, 2 * j - 12);
        } else if (d < 50) {                // shifted wx pair, pos (2j+1, 2j+2)
            int j = d - 36;
            lo = wxv(k, 2 * j - 12);
            hi = wxv(k, 2 * j - 11);
        }
        lutw[i] = pack2(lo, hi);
    }

    // ---- stage halo tile, phase-major: {f16 r|g , u16 koffB=k*204 | f16 b} ----
    for (int i = tid; i < NSTG; i += 256) {
        int r = i / LW;
        int c = i - r * LW;
        int gy = Y0 - HALF + r;
        int gx = X0 - HALF + c;
        float fr = 0.f, fg = 0.f, fb = 0.f;
        uint koffB = 0;
        if (gy >= 0 && gy < IMG_H && gx >= 0 && gx < IMG_W) {
            int p = gy * IMG_W + gx;
            fr = img[p * 3 + 0];
            fg = img[p * 3 + 1];
            fb = img[p * 3 + 2];
            koffB = (uint)(ks[p] * L_KSB);
        }
        uint2 v;
        v.x = pack2(fr, fg);
        v.y = koffB | ((uint)__half_as_ushort(__float2half(fb)) << 16);
        tile[r * LW + (c & 3) * 21 + (c >> 2)] = v;
    }
    __syncthreads();

    const int tx = tid & 15;
    const int ty = tid >> 4;
    const int colbase = tx * 4;
    const int rowbase = ty * 2;
    const int pxbase  = rowbase * LW + tx;   // all per-iter tile reads: pxbase + IMM

    const __half2 hz = h2(0u);
    __half2 a32[2][3], a10[2][3];   // f16 pair accs: (col3,col2), (col1,col0)
    float mc[2][4][3];              // f32 masters [r][col][ch]
    #pragma unroll
    for (int r = 0; r < 2; ++r)
        #pragma unroll
        for (int c = 0; c < 3; ++c) {
            a32[r][c] = hz; a10[r][c] = hz;
            mc[r][0][c] = mc[r][1][c] = mc[r][2][c] = mc[r][3][c] = 0.f;
        }

#define ROW(aa)                                                                    \
    { _Pragma("unroll")                                                            \
      for (int b = 0; b < 24; ++b) {                                               \
          uint2 p = tile[pxbase + (aa) * LW + (b & 3) * 21 + (b >> 2)];            \
          __half2 hx = h2(p.x), hy = h2(p.y);                                      \
          __half2 rr = __low2half2(hx), gg = __high2half2(hx), bb = __high2half2(hy); \
          const char* wp = (const char*)lutw + (p.y & 0xffffu);                    \
          __half2 wy2 = h2(*(const uint*)(wp + 4 * (aa)));                         \
          __half2 wy0 = __low2half2(wy2), wy1 = __high2half2(wy2);                 \
          uint w32, w10;   /* wx pairs: (pos b,b+1)=(col3,col2), (pos b+2,b+3)=(col1,col0) */ \
          if ((b & 1) == 0) {                                                      \
              w32 = *(const uint*)(wp + 4 * (22 + (b >> 1)));                      \
              w10 = *(const uint*)(wp + 4 * (23 + (b >> 1)));                      \
          } else {                                                                 \
              w32 = *(const uint*)(wp + 4 * (36 + ((b - 1) >> 1)));                \
              w10 = *(const uint*)(wp + 4 * (36 + ((b + 1) >> 1)));                \
          }                                                                        \
          __half2 W320 = __hmul2(h2(w32), wy0), W100 = __hmul2(h2(w10), wy0);      \
          __half2 W321 = __hmul2(h2(w32), wy1), W101 = __hmul2(h2(w10), wy1);      \
          a32[0][0] = __hfma2(rr, W320, a32[0][0]);                                \
          a32[0][1] = __hfma2(gg, W320, a32[0][1]);                                \
          a32[0][2] = __hfma2(bb, W320, a32[0][2]);                                \
          a10[0][0] = __hfma2(rr, W100, a10[0][0]);                                \
          a10[0][1] = __hfma2(gg, W100, a10[0][1]);                                \
          a10[0][2] = __hfma2(bb, W100, a10[0][2]);                                \
          a32[1][0] = __hfma2(rr, W321, a32[1][0]);                                \
          a32[1][1] = __hfma2(gg, W321, a32[1][1]);                                \
          a32[1][2] = __hfma2(bb, W321, a32[1][2]);                                \
          a10[1][0] = __hfma2(rr, W101, a10[1][0]);                                \
          a10[1][1] = __hfma2(gg, W101, a10[1][1]);                                \
          a10[1][2] = __hfma2(bb, W101, a10[1][2]);                                \
      } }

#define FLUSH()                                                        \
    { _Pragma("unroll")                                                \
      for (int r = 0; r < 2; ++r) {                                    \
          _Pragma("unroll")                                            \
          for (int c = 0; c < 3; ++c) {                                \
              float2 f3 = __half22float2(a32[r][c]);                   \
              float2 f1 = __half22float2(a10[r][c]);                   \
              mc[r][3][c] += f3.x; mc[r][2][c] += f3.y;                \
              mc[r][1][c] += f1.x; mc[r][0][c] += f1.y;                \
              a32[r][c] = hz; a10[r][c] = hz;                          \
          }                                                            \
      } }

    // 22 source rows, flush f16 partials (<=48 taps) every 2 rows
    #pragma unroll 1
    for (int ap = 0; ap < 11; ++ap) {
        ROW(2 * ap);
        ROW(2 * ap + 1);
        FLUSH();
    }

    // ---- store ----
    #pragma unroll
    for (int r = 0; r < 2; ++r) {
        int gy = Y0 + rowbase + r;
        #pragma unroll
        for (int m = 0; m < 4; ++m) {
            int gx = X0 + colbase + m;
            int o = (gy * IMG_W + gx) * 3;
            out[o + 0] = mc[r][m][0];
            out[o + 1] = mc[r][m][1];
            out[o + 2] = mc[r][m][2];
        }
    }
#undef ROW
#undef FLUSH
}

extern "C" void kernel_launch(void* const* d_in, const int* in_sizes, int n_in,
                              void* d_out, int out_size, void* d_ws, size_t ws_size,
                              hipStream_t stream) {
    const float* img = (const float*)d_in[0];
    const int*   ks  = (const int*)d_in[1];
    float* out = (float*)d_out;

    dim3 grid(IMG_W / TILE_W, IMG_H / TILE_H);   // 32 x 64
    dim3 block(256);
    defocus_imm_kernel<<<grid, block, 0, stream>>>(img, ks, out);
}

// Round 8
// 189.694 us; speedup vs baseline: 3.8084x; 1.0233x over previous
//
#include <hip/hip_runtime.h>
#include <hip/hip_fp16.h>

#define IMG_W 2048
#define IMG_H 2048
#define HALF  10          // max_coc // 2
#define TILE_H 32
#define TILE_W 64
#define LH (TILE_H + 2*HALF)   // 52
#define LW (TILE_W + 2*HALF)   // 84
#define NSTG (LH * LW)         // 4368

// Separable LUT, one 51-dword plane per k (odd stride -> per-lane-k bank-spread):
//   dwords  0..21 : wy pairs; entry a = pack2(wy(a-10), wy(a-11))  (lo->r0, hi->r1)
//   dwords 22..35 : wx pairs;  22+h = pack2(wx(2h-13), wx(2h-12))   (pos 2h,2h+1)
//   dwords 36..49 : wx shifted; 36+j = pack2(wx(2j-12), wx(2j-11))  (pos 2j+1,2j+2)
//   dword  50     : pad
#define L_KSD 51
#define L_KSB 204              // byte plane stride (k*204 fits u16, dword-aligned)
#define L_NDW (22 * L_KSD)     // 1122 dwords = 4488 B

__device__ __forceinline__ __half2 h2(uint u)  { union { uint a; __half2 b; } c; c.a = u; return c.b; }
__device__ __forceinline__ uint pack2(float a, float b) {
    return (uint)__half_as_ushort(__float2half(a)) |
           ((uint)__half_as_ushort(__float2half(b)) << 16);
}
// weight factors: w(k,oy,ox) = wyv(k,oy) * wxv(k,ox); norm folded into wy
__device__ __forceinline__ float wyv(int k, int oy) {
    int a = abs(oy), hk = k >> 1;
    if (a > hk) return 0.f;
    if (k <= 1) return 1.f;
    float kk = (float)(k * k);
    return expf(-(float)(oy * oy) * 18.f / kk) * 5.7295780f / kk;
}
__device__ __forceinline__ float wxv(int k, int ox) {
    int a = abs(ox), hk = k >> 1;
    if (a > hk) return 0.f;
    if (k <= 1) return 1.f;
    float kk = (float)(k * k);
    return expf(-(float)(ox * ox) * 18.f / kk);
}

// VOP3P with explicit op_sel broadcasts (zero splat instructions):
// acc.lo += sel(px)*w.lo ; acc.hi += sel(px)*w.hi   with sel = lo or hi of px
#define FMA_LO(acc, px, w) \
    asm("v_pk_fma_f16 %0, %1, %2, %0 op_sel:[0,0,0] op_sel_hi:[0,1,1]" \
        : "+v"(acc) : "v"(px), "v"(w))
#define FMA_HI(acc, px, w) \
    asm("v_pk_fma_f16 %0, %1, %2, %0 op_sel:[1,0,0] op_sel_hi:[1,1,1]" \
        : "+v"(acc) : "v"(px), "v"(w))
// d = wx2 * splat(lo/hi of wy2)
#define MUL_WYLO(d, wx2, wy2) \
    asm("v_pk_mul_f16 %0, %1, %2 op_sel:[0,0] op_sel_hi:[1,0]" \
        : "=v"(d) : "v"(wx2), "v"(wy2))
#define MUL_WYHI(d, wx2, wy2) \
    asm("v_pk_mul_f16 %0, %1, %2 op_sel:[0,1] op_sel_hi:[1,1]" \
        : "=v"(d) : "v"(wx2), "v"(wy2))

__global__ __launch_bounds__(256)
void defocus_asm_kernel(const float* __restrict__ img,
                        const int* __restrict__ ks,
                        float* __restrict__ out)
{
    __shared__ uint  lutw[L_NDW + 2];   // 4496 B
    __shared__ uint2 tile[NSTG];        // 34944 B; [row][(c&3)*21 + (c>>2)]

    const int tid = threadIdx.x;
    const int X0 = blockIdx.x * TILE_W;
    const int Y0 = blockIdx.y * TILE_H;

    // ---- build separable LUT ----
    for (int i = tid; i < L_NDW; i += 256) {
        int k = i / L_KSD;
        int d = i - k * L_KSD;
        float lo = 0.f, hi = 0.f;
        if (d < 22) {                       // wy pair for source row a=d
            lo = wyv(k, d - 10);
            hi = wyv(k, d - 11);
        } else if (d < 36) {                // wx pair, pos (2h, 2h+1)
            int j = d - 22;
            lo = wxv(k, 2 * j - 13);
            hi = wxv(k, 2 * j - 12);
        } else if (d < 50) {                // shifted wx pair, pos (2j+1, 2j+2)
            int j = d - 36;
            lo = wxv(k, 2 * j - 12);
            hi = wxv(k, 2 * j - 11);
        }
        lutw[i] = pack2(lo, hi);
    }

    // ---- stage halo tile, phase-major: {f16 r|g , u16 koffB=k*204 | f16 b} ----
    for (int i = tid; i < NSTG; i += 256) {
        int r = i / LW;
        int c = i - r * LW;
        int gy = Y0 - HALF + r;
        int gx = X0 - HALF + c;
        float fr = 0.f, fg = 0.f, fb = 0.f;
        uint koffB = 0;
        if (gy >= 0 && gy < IMG_H && gx >= 0 && gx < IMG_W) {
            int p = gy * IMG_W + gx;
            fr = img[p * 3 + 0];
            fg = img[p * 3 + 1];
            fb = img[p * 3 + 2];
            koffB = (uint)(ks[p] * L_KSB);
        }
        uint2 v;
        v.x = pack2(fr, fg);
        v.y = koffB | ((uint)__half_as_ushort(__float2half(fb)) << 16);
        tile[r * LW + (c & 3) * 21 + (c >> 2)] = v;
    }
    __syncthreads();

    const int tx = tid & 15;
    const int ty = tid >> 4;
    const int colbase = tx * 4;
    const int rowbase = ty * 2;
    const int pxbase  = rowbase * LW + tx;   // all per-iter tile reads: pxbase + IMM

    // f16 pair accumulators as raw dwords: A32[r][ch]=(col3,col2), A10[r][ch]=(col1,col0)
    uint A32[2][3] = {{0,0,0},{0,0,0}}, A10[2][3] = {{0,0,0},{0,0,0}};
    float mc[2][4][3];              // f32 masters [r][col][ch]
    #pragma unroll
    for (int r = 0; r < 2; ++r)
        #pragma unroll
        for (int c = 0; c < 3; ++c)
            mc[r][0][c] = mc[r][1][c] = mc[r][2][c] = mc[r][3][c] = 0.f;

#define ROW(aa)                                                                    \
    { _Pragma("unroll")                                                            \
      for (int b = 0; b < 24; ++b) {                                               \
          uint2 p = tile[pxbase + (aa) * LW + (b & 3) * 21 + (b >> 2)];            \
          const char* wp = (const char*)lutw + (p.y & 0xffffu);                    \
          uint wy2 = *(const uint*)(wp + 4 * (aa));                                \
          uint w32, w10;   /* wx pairs: (pos b,b+1)=(col3,col2), (pos b+2,b+3)=(col1,col0) */ \
          if ((b & 1) == 0) {                                                      \
              w32 = *(const uint*)(wp + 4 * (22 + (b >> 1)));                      \
              w10 = *(const uint*)(wp + 4 * (23 + (b >> 1)));                      \
          } else {                                                                 \
              w32 = *(const uint*)(wp + 4 * (36 + ((b - 1) >> 1)));                \
              w10 = *(const uint*)(wp + 4 * (36 + ((b + 1) >> 1)));                \
          }                                                                        \
          uint W320, W100, W321, W101;                                             \
          MUL_WYLO(W320, w32, wy2);                                                \
          MUL_WYLO(W100, w10, wy2);                                                \
          MUL_WYHI(W321, w32, wy2);                                                \
          MUL_WYHI(W101, w10, wy2);                                                \
          FMA_LO(A32[0][0], p.x, W320);                                            \
          FMA_HI(A32[0][1], p.x, W320);                                            \
          FMA_HI(A32[0][2], p.y, W320);                                            \
          FMA_LO(A10[0][0], p.x, W100);                                            \
          FMA_HI(A10[0][1], p.x, W100);                                            \
          FMA_HI(A10[0][2], p.y, W100);                                            \
          FMA_LO(A32[1][0], p.x, W321);                                            \
          FMA_HI(A32[1][1], p.x, W321);                                            \
          FMA_HI(A32[1][2], p.y, W321);                                            \
          FMA_LO(A10[1][0], p.x, W101);                                            \
          FMA_HI(A10[1][1], p.x, W101);                                            \
          FMA_HI(A10[1][2], p.y, W101);                                            \
      } }

#define FLUSH()                                                        \
    { _Pragma("unroll")                                                \
      for (int r = 0; r < 2; ++r) {                                    \
          _Pragma("unroll")                                            \
          for (int c = 0; c < 3; ++c) {                                \
              float2 f3 = __half22float2(h2(A32[r][c]));               \
              float2 f1 = __half22float2(h2(A10[r][c]));               \
              mc[r][3][c] += f3.x; mc[r][2][c] += f3.y;                \
              mc[r][1][c] += f1.x; mc[r][0][c] += f1.y;                \
              A32[r][c] = 0; A10[r][c] = 0;                            \
          }                                                            \
      } }

    // 22 source rows, flush f16 partials (<=48 taps) every 2 rows
    #pragma unroll 1
    for (int ap = 0; ap < 11; ++ap) {
        ROW(2 * ap);
        ROW(2 * ap + 1);
        FLUSH();
    }

    // ---- store ----
    #pragma unroll
    for (int r = 0; r < 2; ++r) {
        int gy = Y0 + rowbase + r;
        #pragma unroll
        for (int m = 0; m < 4; ++m) {
            int gx = X0 + colbase + m;
            int o = (gy * IMG_W + gx) * 3;
            out[o + 0] = mc[r][m][0];
            out[o + 1] = mc[r][m][1];
            out[o + 2] = mc[r][m][2];
        }
    }
#undef ROW
#undef FLUSH
}

extern "C" void kernel_launch(void* const* d_in, const int* in_sizes, int n_in,
                              void* d_out, int out_size, void* d_ws, size_t ws_size,
                              hipStream_t stream) {
    const float* img = (const float*)d_in[0];
    const int*   ks  = (const int*)d_in[1];
    float* out = (float*)d_out;

    dim3 grid(IMG_W / TILE_W, IMG_H / TILE_H);   // 32 x 64
    dim3 block(256);
    defocus_asm_kernel<<<grid, block, 0, stream>>>(img, ks, out);
}